// Round 1
// baseline (87.315 us; speedup 1.0000x reference)
//
#include <hip/hip_runtime.h>

// Exact KNN (faiss-equivalent, (dist,idx)-lexicographic ties) + fused neighbor
// feature sum. N=65536 pts on 128^3 int grid, K=16, C=64.
//
// Cells = 4^3 coords -> 32^3 = 32768 cells, ~2 pts/cell. Key = (d2<<16)|idx
// (d2 <= 48387 < 2^16): unsigned order == (dist, idx) lexicographic.
//
// Prologue fused: ONE build kernel (256 blocks x 256 thr) does histogram ->
// hierarchical scan -> scatter with 3 device-scope spin barriers. 256 blocks
// <= 256 CUs and it is the only kernel on the stream => all blocks resident
// by construction, spin barrier cannot deadlock; plain launch = capture-safe.
// All cross-block data (counts/bsums/cursors) via AGENT-scope atomics so
// per-XCD L2 non-coherence cannot serve stale lines. Barrier counter zeroed
// by the memset each replay.
//
// knn_search: wave = 8 queries x 8 slices. Main scan = quadrant-aligned
// 4x4x4 cell box, SHIFT-clamped to the grid (origin clamp [0,28]) so the box
// is always full 4x4x4. Guarantee: uncovered min-d2 >= 49. Each slice-lane
// owns 2 whole rows; two candidate streams interleaved. Per-lane sorted
// top-16 via med3 insert network. Merge tree (masks 8,16,32); the FINAL
// merge keeps only the min-half (bitonic, unsorted) since the gather is a
// set-sum -- redo bound via max-tree; the cold redo path (P~1e-7/query)
// re-sorts first, then proceeds exactly as before.
// Gather fused: lane = 4 channels x 16 lanes/query, 2 passes x 4 queries;
// float4 feature-row loads; output written directly.

typedef unsigned int uint;
typedef unsigned short ushort;
typedef short short2v __attribute__((ext_vector_type(2)));

#define NPTS   65536
#define NCELL  32768
#define BBLK   256
#define BTPB   256

static __device__ inline short2v u2s(uint v) { union { uint u; short2v s; } c; c.u = v; return c.s; }
static __device__ inline uint s2u(short2v v) { union { uint u; short2v s; } c; c.s = v; return c.u; }

static __device__ inline int dot2acc(short2v a, short2v b, int c) {
#if __has_builtin(__builtin_amdgcn_sdot2)
    return __builtin_amdgcn_sdot2(a, b, c, false);
#else
    return (int)a.x * (int)b.x + (int)a.y * (int)b.y + c;
#endif
}

// Arrive-and-spin grid barrier. Safe because all BBLK blocks are resident
// (BBLK <= #CUs, sole kernel). target = BBLK * phase.
static __device__ __forceinline__ void gridbar(uint* bar, uint target) {
    __syncthreads();
    if (threadIdx.x == 0) {
        __hip_atomic_fetch_add(bar, 1u, __ATOMIC_ACQ_REL, __HIP_MEMORY_SCOPE_AGENT);
        while (__hip_atomic_load(bar, __ATOMIC_ACQUIRE, __HIP_MEMORY_SCOPE_AGENT) < target)
            __builtin_amdgcn_s_sleep(1);
    }
    __syncthreads();
}

__global__ __launch_bounds__(BTPB) void build(const int* __restrict__ coords,
                                              uint* __restrict__ bar,
                                              uint* __restrict__ counts,
                                              uint* __restrict__ starts,
                                              uint* __restrict__ cursors,
                                              uint2* __restrict__ sorted) {
    __shared__ uint wsum[4];
    __shared__ uint rsum[4];
    int b = blockIdx.x, tid = threadIdx.x;
    int i = b * BTPB + tid;
    int lane = tid & 63, wv = tid >> 6;

    // ---- phase 1: histogram (counts zeroed by the preceding memset) ----
    int x = coords[3 * i + 0], y = coords[3 * i + 1], z = coords[3 * i + 2];
    int cell = (x >> 2) | ((y >> 2) << 5) | ((z >> 2) << 10);
    atomicAdd(&counts[cell], 1u);
    gridbar(bar, BBLK);

    // ---- phase 2a: block-local scan, 256 cells/block (blocks 0..127) ----
    uint* bsums = (uint*)sorted;   // 128 scratch uints; clobbered in phase 3
    uint c = 0, excl = 0;
    if (b < 128) {
        int t2 = b * 256 + tid;    // cell id
        c = __hip_atomic_load(&counts[t2], __ATOMIC_RELAXED, __HIP_MEMORY_SCOPE_AGENT);
        uint v = c;
#pragma unroll
        for (int off = 1; off < 64; off <<= 1) {
            uint u = __shfl_up(v, off, 64);
            if (lane >= off) v += u;
        }
        if (lane == 63) wsum[wv] = v;
        __syncthreads();
        uint woff = 0, btot = 0;
#pragma unroll
        for (int j = 0; j < 4; ++j) {
            uint w = wsum[j];
            woff += (j < wv) ? w : 0u;
            btot += w;
        }
        excl = woff + v - c;       // block-local exclusive prefix
        if (tid == 0)
            __hip_atomic_store(&bsums[b], btot, __ATOMIC_RELAXED, __HIP_MEMORY_SCOPE_AGENT);
    }
    gridbar(bar, 2 * BBLK);

    // ---- phase 2b: cross-block offset, write starts/cursors ----
    if (b < 128) {
        uint s = 0;
        if (tid < 128 && tid < b)
            s = __hip_atomic_load(&bsums[tid], __ATOMIC_RELAXED, __HIP_MEMORY_SCOPE_AGENT);
#pragma unroll
        for (int off = 32; off; off >>= 1) s += __shfl_xor(s, off, 64);
        if (lane == 0) rsum[wv] = s;
        __syncthreads();
        uint blockoff = rsum[0] + rsum[1] + rsum[2] + rsum[3];
        int t2 = b * 256 + tid;
        uint st = blockoff + excl;
        starts[t2] = st;
        __hip_atomic_store(&cursors[t2], st, __ATOMIC_RELAXED, __HIP_MEMORY_SCOPE_AGENT);
        if (t2 == NCELL - 1) starts[NCELL] = st + c;   // = 65536
    }
    gridbar(bar, 3 * BBLK);

    // ---- phase 3: scatter (x,y,z,cell kept in registers from phase 1) ----
    uint pos = atomicAdd(&cursors[cell], 1u);
    sorted[pos] = make_uint2((uint)(x | (y << 16)), (uint)(i | (z << 16)));
}

__global__ __launch_bounds__(128, 8) void knn_search(const uint* __restrict__ starts,
                                                     const uint2* __restrict__ sorted,
                                                     const float* __restrict__ feat,
                                                     float* __restrict__ out) {
    // XCD-chunked swizzle: consecutive logical blocks -> same XCD L2.
    int blk  = (blockIdx.x & 7) * 512 + (blockIdx.x >> 3);   // 4096 blocks
    int wave = threadIdx.x >> 6;
    int lane = threadIdx.x & 63;
    int qslot = lane & 7;
    int slice = lane >> 3;
    int qpos = blk * 16 + wave * 8 + qslot;

    uint2 me = sorted[qpos];
    uint qxy = me.x;                       // qx | qy<<16
    uint qzp = me.y & 0xFFFF0000u;         // qz<<16
    uint qidx = me.y & 0xFFFFu;            // original index
    int qx = (int)(me.x & 0xFFFFu);
    int qy = (int)(me.x >> 16);
    int qz = (int)(me.y >> 16);
    int cx = qx >> 2, cy = qy >> 2, cz = qz >> 2;

    uint k[16];
#pragma unroll
    for (int j = 0; j < 16; ++j) k[j] = 0xFFFFFFFFu;

    auto insert1 = [&](uint2 pt) {
        short2v A = u2s(pt.x) - u2s(qxy);          // (dx, dy)
        short2v B = u2s(pt.y) - u2s(qzp);          // (idx, dz)
        uint Bu = s2u(B);
        short2v Bm = u2s(Bu & 0xFFFF0000u);        // (0, dz)
        int d2 = dot2acc(A, A, dot2acc(Bm, Bm, 0));
        uint key = ((uint)d2 << 16) + (Bu & 0xFFFFu);
        // in-place descending med3 chain: 15 independent ops (reads old j-1)
#pragma unroll
        for (int j = 15; j >= 1; --j)
            asm("v_med3_u32 %0, %1, %2, %3"
                : "=v"(k[j]) : "v"(k[j - 1]), "v"(k[j]), "v"(key));
        k[0] = min(k[0], key);
    };

    // sliced scan (stride 8 across slices) -- used only by the cold redo path
    auto scan8 = [&](uint p0, uint p1) {
        for (uint p = p0 + (uint)slice; p < p1; p += 8u) insert1(sorted[p]);
    };

    // bitonic min-half with partner lane (lane ^ mask): k becomes a bitonic
    // sequence holding the exact top-16 SET of the pair
    auto merge_min = [&](int mask) {
        uint b[16];
#pragma unroll
        for (int j = 0; j < 16; ++j) b[j] = __shfl_xor(k[j], mask, 64);
#pragma unroll
        for (int j = 0; j < 16; ++j) k[j] = min(k[j], b[15 - j]);
    };
    // bitonic cleanup: sorts the bitonic sequence ascending
    auto clean = [&]() {
#pragma unroll
        for (int d = 8; d >= 1; d >>= 1) {
#pragma unroll
            for (int i = 0; i < 16; ++i) {
                if ((i & d) == 0) {
                    uint lo = min(k[i], k[i + d]);
                    uint hi = max(k[i], k[i + d]);
                    k[i] = lo;
                    k[i + d] = hi;
                }
            }
        }
    };
    auto merge = [&](int mask) { merge_min(mask); clean(); };
    auto merge_all = [&]() { merge(8); merge(16); merge(32); };

    // ---- quadrant-aligned 4x4x4 box, SHIFT-clamped (always full size) ----
    int xa = min(max(cx - ((qx & 3) < 2 ? 2 : 1), 0), 28);
    int ya = min(max(cy - ((qy & 3) < 2 ? 2 : 1), 0), 28);
    int za = min(max(cz - ((qz & 3) < 2 ? 2 : 1), 0), 28);

    // lane owns rows rid = slice and slice+8;  rid -> (y = ya+(rid&3), z = za+(rid>>2))
    {
        int rbA = ((ya + (slice & 3)) << 5) | ((za + (slice >> 2)) << 10);
        int rbB = ((ya + (slice & 3)) << 5) | ((za + 2 + (slice >> 2)) << 10);
        uint pA = starts[rbA + xa], eA = starts[rbA + xa + 4];
        uint pB = starts[rbB + xa], eB = starts[rbB + xa + 4];
        while (__any((pA < eA) || (pB < eB))) {
            bool a = pA < eA, b = pB < eB;
            uint2 ptA, ptB;
            if (a) ptA = sorted[pA];
            if (b) ptB = sorted[pB];
            pA += a ? 1u : 0u;
            pB += b ? 1u : 0u;
            if (a) insert1(ptA);
            if (b) insert1(ptB);
        }
    }
    // exact top-16 SET over the box (final merge leaves k bitonic-unsorted;
    // the gather is a set-sum so order is irrelevant on the hot path)
    merge(8); merge(16); merge_min(32);
    uint mx = k[0];
#pragma unroll
    for (int j = 1; j < 16; ++j) mx = max(mx, k[j]);

    // ---- cold redo: uncovered space has min-d2 >= 49 (P ~ 1e-7/query) ----
    bool redo = (mx >> 16) >= 49u;
    if (__any(redo)) {
        clean();   // restore sorted order: merge machinery needs sorted inputs
        // triggered queries: discard everything, rescan from scratch (sliced).
        // others: keep slice 0 only (slices!=0 must reset before re-merge).
        if (redo || slice != 0) {
#pragma unroll
            for (int j = 0; j < 16; ++j) k[j] = 0xFFFFFFFFu;
        }
        if (redo) {
            int xl = max(cx - 2, 0), xh = min(cx + 2, 31);
            int yl = max(cy - 2, 0), yh = min(cy + 2, 31);
            int zl = max(cz - 2, 0), zh = min(cz + 2, 31);
            for (int z = zl; z <= zh; ++z)
                for (int y = yl; y <= yh; ++y) {
                    int rb = (y << 5) | (z << 10);
                    scan8(starts[rb + xl], starts[rb + xh + 1]);
                }
        }
        merge_all();
        for (int r = 3; r < 32; ++r) {
            uint b = (uint)(4 * r - 3);
            bool active = (k[15] >> 16) >= b * b;
            if (!__any(active)) break;
            if (slice != 0) {
#pragma unroll
                for (int j = 0; j < 16; ++j) k[j] = 0xFFFFFFFFu;
            }
            if (active) {
                int z0 = cz - r < 0 ? 0 : cz - r;
                int z1 = cz + r > 31 ? 31 : cz + r;
                for (int z = z0; z <= z1; ++z) {
                    bool zface = (z == cz - r) || (z == cz + r);
                    int y0 = cy - r < 0 ? 0 : cy - r;
                    int y1 = cy + r > 31 ? 31 : cy + r;
                    for (int y = y0; y <= y1; ++y) {
                        bool face = zface || (y == cy - r) || (y == cy + r);
                        int rb = (y << 5) | (z << 10);
                        if (face) {
                            int x0 = cx - r < 0 ? 0 : cx - r;
                            int x1 = cx + r > 31 ? 31 : cx + r;
                            scan8(starts[rb + x0], starts[rb + x1 + 1]);
                        } else {
                            int xL = cx - r;
                            if (xL >= 0) scan8(starts[rb + xL], starts[rb + xL + 1]);
                            int xR = cx + r;
                            if (xR <= 31) scan8(starts[rb + xR], starts[rb + xR + 1]);
                        }
                    }
                }
            }
            merge_all();
        }
    }

    // ---- fused gather: float4 channels, 2 passes x 4 queries ----
    uint ki[16];
#pragma unroll
    for (int j = 0; j < 16; ++j) ki[j] = k[j] & 0xFFFFu;

    int ch = lane & 15;          // float4 channel group (4 channels)
    int qg = lane >> 4;          // query within pass
#pragma unroll
    for (int p = 0; p < 2; ++p) {
        int qs = p * 4 + qg;
        uint qorig = __shfl(qidx, qs, 64);
        float4 acc = make_float4(0.f, 0.f, 0.f, 0.f);
#pragma unroll
        for (int j = 0; j < 16; ++j) {
            uint nj = __shfl(ki[j], qs, 64);
            float4 v = reinterpret_cast<const float4*>(feat)[nj * 16u + (uint)ch];
            acc.x += v.x; acc.y += v.y; acc.z += v.z; acc.w += v.w;
        }
        reinterpret_cast<float4*>(out)[qorig * 16u + (uint)ch] = acc;
    }
}

extern "C" void kernel_launch(void* const* d_in, const int* in_sizes, int n_in,
                              void* d_out, int out_size, void* d_ws, size_t ws_size,
                              hipStream_t stream) {
    const int*   coords = (const int*)d_in[0];
    const float* feat   = (const float*)d_in[1];
    float*       out    = (float*)d_out;

    uint* W = (uint*)d_ws;
    uint*  bar     = W;                       // 8 uints (1 used), memset-zeroed
    uint*  counts  = W + 8;                   // 32768, memset-zeroed
    uint*  starts  = W + 32776;               // 32769
    uint*  cursors = W + 65548;               // 32768 (16B aligned)
    uint2* sorted  = (uint2*)(W + 98316);     // 65536 * 8 B (8B aligned)

    hipMemsetAsync(W, 0, (8 + NCELL) * sizeof(uint), stream);
    build<<<BBLK, BTPB, 0, stream>>>(coords, bar, counts, starts, cursors, sorted);
    knn_search<<<4096, 128, 0, stream>>>(starts, sorted, feat, out);
}

// Round 2
// 76.122 us; speedup vs baseline: 1.1470x; 1.1470x over previous
//
#include <hip/hip_runtime.h>

// Exact KNN (faiss-equivalent, (dist,idx)-lexicographic ties) + fused neighbor
// feature sum. N=65536 pts on 128^3 int grid, K=16, C=64.
//
// Cells = 4^3 coords -> 32^3 = 32768 cells, ~2 pts/cell. Key = (d2<<16)|idx
// (d2 <= 48387 < 2^16): unsigned order == (dist, idx) lexicographic.
//
// Prologue fused: ONE build kernel (256 blocks x 256 thr) does histogram ->
// hierarchical scan -> scatter with 3 device-scope spin barriers. 256 blocks
// <= 256 CUs and it is the only kernel on the stream => all blocks resident
// by construction, spin barrier cannot deadlock; plain launch = capture-safe.
//
// BARRIER COST LESSON (round 1): agent-scope ACQUIRE/RELEASE atomics emit
// per-XCD L2 invalidate (buffer_inv) / writeback (buffer_wbl2). Spinning on
// an acquire load = one L2 invalidate PER POLL from 256 waves -> ~15us per
// barrier. Since ALL cross-block data here moves via sc1 atomics (which
// bypass the per-XCD L2 and execute at the coherence point), no cache
// maintenance is needed at all: release == s_waitcnt vmcnt(0) (data atomics
// complete before arrival visible), and the spin polls with a RELAXED
// fetch_add(0) (RMW always executes at the coherence point -> never stale,
// never hangs) + s_sleep backoff.
//
// knn_search: wave = 8 queries x 8 slices. Main scan = quadrant-aligned
// 4x4x4 cell box, SHIFT-clamped to the grid (origin clamp [0,28]) so the box
// is always full 4x4x4. Guarantee: uncovered min-d2 >= 49. Each slice-lane
// owns 2 whole rows; two candidate streams interleaved. Per-lane sorted
// top-16 via med3 insert network. Merge tree (masks 8,16,32); the FINAL
// merge keeps only the min-half (bitonic, unsorted) since the gather is a
// set-sum -- redo bound via max-tree; the cold redo path (P~1e-7/query)
// re-sorts first, then proceeds exactly as before.
// Gather fused: lane = 4 channels x 16 lanes/query, 2 passes x 4 queries;
// float4 feature-row loads; output written directly.

typedef unsigned int uint;
typedef unsigned short ushort;
typedef short short2v __attribute__((ext_vector_type(2)));

#define NPTS   65536
#define NCELL  32768
#define BBLK   256
#define BTPB   256

static __device__ inline short2v u2s(uint v) { union { uint u; short2v s; } c; c.u = v; return c.s; }
static __device__ inline uint s2u(short2v v) { union { uint u; short2v s; } c; c.s = v; return c.u; }

static __device__ inline int dot2acc(short2v a, short2v b, int c) {
#if __has_builtin(__builtin_amdgcn_sdot2)
    return __builtin_amdgcn_sdot2(a, b, c, false);
#else
    return (int)a.x * (int)b.x + (int)a.y * (int)b.y + c;
#endif
}

// Arrive-and-spin grid barrier. Safe because all BBLK blocks are resident
// (BBLK <= #CUs, sole kernel). target = BBLK * phase.
// No acquire/release cache ops (see header comment): waitcnt-ordered relaxed
// RMWs at the coherence point are sufficient AND necessary here.
static __device__ __forceinline__ void gridbar(uint* bar, uint target) {
    __syncthreads();
    if (threadIdx.x == 0) {
        // all prior sc1 data atomics complete before our arrival is visible
        asm volatile("s_waitcnt vmcnt(0)" ::: "memory");
        __hip_atomic_fetch_add(bar, 1u, __ATOMIC_RELAXED, __HIP_MEMORY_SCOPE_AGENT);
        // poll with an RMW (+0): always served at the coherence point, so it
        // can never read a stale per-XCD L2 line; ~0.2us backoff keeps the
        // line cool.
        while (__hip_atomic_fetch_add(bar, 0u, __ATOMIC_RELAXED, __HIP_MEMORY_SCOPE_AGENT) < target)
            __builtin_amdgcn_s_sleep(8);
    }
    __syncthreads();
}

__global__ __launch_bounds__(BTPB) void build(const int* __restrict__ coords,
                                              uint* __restrict__ bar,
                                              uint* __restrict__ counts,
                                              uint* __restrict__ starts,
                                              uint* __restrict__ cursors,
                                              uint2* __restrict__ sorted) {
    __shared__ uint wsum[4];
    __shared__ uint rsum[4];
    int b = blockIdx.x, tid = threadIdx.x;
    int i = b * BTPB + tid;
    int lane = tid & 63, wv = tid >> 6;

    // ---- phase 1: histogram (counts zeroed by the preceding memset) ----
    int x = coords[3 * i + 0], y = coords[3 * i + 1], z = coords[3 * i + 2];
    int cell = (x >> 2) | ((y >> 2) << 5) | ((z >> 2) << 10);
    atomicAdd(&counts[cell], 1u);
    gridbar(bar, BBLK);

    // ---- phase 2a: block-local scan, 256 cells/block (blocks 0..127) ----
    uint* bsums = (uint*)sorted;   // 128 scratch uints; clobbered in phase 3
    uint c = 0, excl = 0;
    if (b < 128) {
        int t2 = b * 256 + tid;    // cell id
        c = __hip_atomic_load(&counts[t2], __ATOMIC_RELAXED, __HIP_MEMORY_SCOPE_AGENT);
        uint v = c;
#pragma unroll
        for (int off = 1; off < 64; off <<= 1) {
            uint u = __shfl_up(v, off, 64);
            if (lane >= off) v += u;
        }
        if (lane == 63) wsum[wv] = v;
        __syncthreads();
        uint woff = 0, btot = 0;
#pragma unroll
        for (int j = 0; j < 4; ++j) {
            uint w = wsum[j];
            woff += (j < wv) ? w : 0u;
            btot += w;
        }
        excl = woff + v - c;       // block-local exclusive prefix
        if (tid == 0)
            __hip_atomic_store(&bsums[b], btot, __ATOMIC_RELAXED, __HIP_MEMORY_SCOPE_AGENT);
    }
    gridbar(bar, 2 * BBLK);

    // ---- phase 2b: cross-block offset, write starts/cursors ----
    if (b < 128) {
        uint s = 0;
        if (tid < 128 && tid < b)
            s = __hip_atomic_load(&bsums[tid], __ATOMIC_RELAXED, __HIP_MEMORY_SCOPE_AGENT);
#pragma unroll
        for (int off = 32; off; off >>= 1) s += __shfl_xor(s, off, 64);
        if (lane == 0) rsum[wv] = s;
        __syncthreads();
        uint blockoff = rsum[0] + rsum[1] + rsum[2] + rsum[3];
        int t2 = b * 256 + tid;
        uint st = blockoff + excl;
        starts[t2] = st;
        __hip_atomic_store(&cursors[t2], st, __ATOMIC_RELAXED, __HIP_MEMORY_SCOPE_AGENT);
        if (t2 == NCELL - 1) starts[NCELL] = st + c;   // = 65536
    }
    gridbar(bar, 3 * BBLK);

    // ---- phase 3: scatter (x,y,z,cell kept in registers from phase 1) ----
    uint pos = atomicAdd(&cursors[cell], 1u);
    sorted[pos] = make_uint2((uint)(x | (y << 16)), (uint)(i | (z << 16)));
}

__global__ __launch_bounds__(128, 8) void knn_search(const uint* __restrict__ starts,
                                                     const uint2* __restrict__ sorted,
                                                     const float* __restrict__ feat,
                                                     float* __restrict__ out) {
    // XCD-chunked swizzle: consecutive logical blocks -> same XCD L2.
    int blk  = (blockIdx.x & 7) * 512 + (blockIdx.x >> 3);   // 4096 blocks
    int wave = threadIdx.x >> 6;
    int lane = threadIdx.x & 63;
    int qslot = lane & 7;
    int slice = lane >> 3;
    int qpos = blk * 16 + wave * 8 + qslot;

    uint2 me = sorted[qpos];
    uint qxy = me.x;                       // qx | qy<<16
    uint qzp = me.y & 0xFFFF0000u;         // qz<<16
    uint qidx = me.y & 0xFFFFu;            // original index
    int qx = (int)(me.x & 0xFFFFu);
    int qy = (int)(me.x >> 16);
    int qz = (int)(me.y >> 16);
    int cx = qx >> 2, cy = qy >> 2, cz = qz >> 2;

    uint k[16];
#pragma unroll
    for (int j = 0; j < 16; ++j) k[j] = 0xFFFFFFFFu;

    auto insert1 = [&](uint2 pt) {
        short2v A = u2s(pt.x) - u2s(qxy);          // (dx, dy)
        short2v B = u2s(pt.y) - u2s(qzp);          // (idx, dz)
        uint Bu = s2u(B);
        short2v Bm = u2s(Bu & 0xFFFF0000u);        // (0, dz)
        int d2 = dot2acc(A, A, dot2acc(Bm, Bm, 0));
        uint key = ((uint)d2 << 16) + (Bu & 0xFFFFu);
        // in-place descending med3 chain: 15 independent ops (reads old j-1)
#pragma unroll
        for (int j = 15; j >= 1; --j)
            asm("v_med3_u32 %0, %1, %2, %3"
                : "=v"(k[j]) : "v"(k[j - 1]), "v"(k[j]), "v"(key));
        k[0] = min(k[0], key);
    };

    // sliced scan (stride 8 across slices) -- used only by the cold redo path
    auto scan8 = [&](uint p0, uint p1) {
        for (uint p = p0 + (uint)slice; p < p1; p += 8u) insert1(sorted[p]);
    };

    // bitonic min-half with partner lane (lane ^ mask): k becomes a bitonic
    // sequence holding the exact top-16 SET of the pair
    auto merge_min = [&](int mask) {
        uint b[16];
#pragma unroll
        for (int j = 0; j < 16; ++j) b[j] = __shfl_xor(k[j], mask, 64);
#pragma unroll
        for (int j = 0; j < 16; ++j) k[j] = min(k[j], b[15 - j]);
    };
    // bitonic cleanup: sorts the bitonic sequence ascending
    auto clean = [&]() {
#pragma unroll
        for (int d = 8; d >= 1; d >>= 1) {
#pragma unroll
            for (int i = 0; i < 16; ++i) {
                if ((i & d) == 0) {
                    uint lo = min(k[i], k[i + d]);
                    uint hi = max(k[i], k[i + d]);
                    k[i] = lo;
                    k[i + d] = hi;
                }
            }
        }
    };
    auto merge = [&](int mask) { merge_min(mask); clean(); };
    auto merge_all = [&]() { merge(8); merge(16); merge(32); };

    // ---- quadrant-aligned 4x4x4 box, SHIFT-clamped (always full size) ----
    int xa = min(max(cx - ((qx & 3) < 2 ? 2 : 1), 0), 28);
    int ya = min(max(cy - ((qy & 3) < 2 ? 2 : 1), 0), 28);
    int za = min(max(cz - ((qz & 3) < 2 ? 2 : 1), 0), 28);

    // lane owns rows rid = slice and slice+8;  rid -> (y = ya+(rid&3), z = za+(rid>>2))
    {
        int rbA = ((ya + (slice & 3)) << 5) | ((za + (slice >> 2)) << 10);
        int rbB = ((ya + (slice & 3)) << 5) | ((za + 2 + (slice >> 2)) << 10);
        uint pA = starts[rbA + xa], eA = starts[rbA + xa + 4];
        uint pB = starts[rbB + xa], eB = starts[rbB + xa + 4];
        while (__any((pA < eA) || (pB < eB))) {
            bool a = pA < eA, b = pB < eB;
            uint2 ptA, ptB;
            if (a) ptA = sorted[pA];
            if (b) ptB = sorted[pB];
            pA += a ? 1u : 0u;
            pB += b ? 1u : 0u;
            if (a) insert1(ptA);
            if (b) insert1(ptB);
        }
    }
    // exact top-16 SET over the box (final merge leaves k bitonic-unsorted;
    // the gather is a set-sum so order is irrelevant on the hot path)
    merge(8); merge(16); merge_min(32);
    uint mx = k[0];
#pragma unroll
    for (int j = 1; j < 16; ++j) mx = max(mx, k[j]);

    // ---- cold redo: uncovered space has min-d2 >= 49 (P ~ 1e-7/query) ----
    bool redo = (mx >> 16) >= 49u;
    if (__any(redo)) {
        clean();   // restore sorted order: merge machinery needs sorted inputs
        // triggered queries: discard everything, rescan from scratch (sliced).
        // others: keep slice 0 only (slices!=0 must reset before re-merge).
        if (redo || slice != 0) {
#pragma unroll
            for (int j = 0; j < 16; ++j) k[j] = 0xFFFFFFFFu;
        }
        if (redo) {
            int xl = max(cx - 2, 0), xh = min(cx + 2, 31);
            int yl = max(cy - 2, 0), yh = min(cy + 2, 31);
            int zl = max(cz - 2, 0), zh = min(cz + 2, 31);
            for (int z = zl; z <= zh; ++z)
                for (int y = yl; y <= yh; ++y) {
                    int rb = (y << 5) | (z << 10);
                    scan8(starts[rb + xl], starts[rb + xh + 1]);
                }
        }
        merge_all();
        for (int r = 3; r < 32; ++r) {
            uint b = (uint)(4 * r - 3);
            bool active = (k[15] >> 16) >= b * b;
            if (!__any(active)) break;
            if (slice != 0) {
#pragma unroll
                for (int j = 0; j < 16; ++j) k[j] = 0xFFFFFFFFu;
            }
            if (active) {
                int z0 = cz - r < 0 ? 0 : cz - r;
                int z1 = cz + r > 31 ? 31 : cz + r;
                for (int z = z0; z <= z1; ++z) {
                    bool zface = (z == cz - r) || (z == cz + r);
                    int y0 = cy - r < 0 ? 0 : cy - r;
                    int y1 = cy + r > 31 ? 31 : cy + r;
                    for (int y = y0; y <= y1; ++y) {
                        bool face = zface || (y == cy - r) || (y == cy + r);
                        int rb = (y << 5) | (z << 10);
                        if (face) {
                            int x0 = cx - r < 0 ? 0 : cx - r;
                            int x1 = cx + r > 31 ? 31 : cx + r;
                            scan8(starts[rb + x0], starts[rb + x1 + 1]);
                        } else {
                            int xL = cx - r;
                            if (xL >= 0) scan8(starts[rb + xL], starts[rb + xL + 1]);
                            int xR = cx + r;
                            if (xR <= 31) scan8(starts[rb + xR], starts[rb + xR + 1]);
                        }
                    }
                }
            }
            merge_all();
        }
    }

    // ---- fused gather: float4 channels, 2 passes x 4 queries ----
    uint ki[16];
#pragma unroll
    for (int j = 0; j < 16; ++j) ki[j] = k[j] & 0xFFFFu;

    int ch = lane & 15;          // float4 channel group (4 channels)
    int qg = lane >> 4;          // query within pass
#pragma unroll
    for (int p = 0; p < 2; ++p) {
        int qs = p * 4 + qg;
        uint qorig = __shfl(qidx, qs, 64);
        float4 acc = make_float4(0.f, 0.f, 0.f, 0.f);
#pragma unroll
        for (int j = 0; j < 16; ++j) {
            uint nj = __shfl(ki[j], qs, 64);
            float4 v = reinterpret_cast<const float4*>(feat)[nj * 16u + (uint)ch];
            acc.x += v.x; acc.y += v.y; acc.z += v.z; acc.w += v.w;
        }
        reinterpret_cast<float4*>(out)[qorig * 16u + (uint)ch] = acc;
    }
}

extern "C" void kernel_launch(void* const* d_in, const int* in_sizes, int n_in,
                              void* d_out, int out_size, void* d_ws, size_t ws_size,
                              hipStream_t stream) {
    const int*   coords = (const int*)d_in[0];
    const float* feat   = (const float*)d_in[1];
    float*       out    = (float*)d_out;

    uint* W = (uint*)d_ws;
    uint*  bar     = W;                       // 8 uints (1 used), memset-zeroed
    uint*  counts  = W + 8;                   // 32768, memset-zeroed
    uint*  starts  = W + 32776;               // 32769
    uint*  cursors = W + 65548;               // 32768 (16B aligned)
    uint2* sorted  = (uint2*)(W + 98316);     // 65536 * 8 B (8B aligned)

    hipMemsetAsync(W, 0, (8 + NCELL) * sizeof(uint), stream);
    build<<<BBLK, BTPB, 0, stream>>>(coords, bar, counts, starts, cursors, sorted);
    knn_search<<<4096, 128, 0, stream>>>(starts, sorted, feat, out);
}

// Round 3
// 75.186 us; speedup vs baseline: 1.1613x; 1.0124x over previous
//
#include <hip/hip_runtime.h>

// Exact KNN (faiss-equivalent, (dist,idx)-lexicographic ties) + fused neighbor
// feature sum. N=65536 pts on 128^3 int grid, K=16, C=64.
//
// Cells = 4^3 coords -> 32^3 = 32768 cells, ~2 pts/cell. Key = (d2<<16)|idx
// (d2 <= 48387 < 2^16): unsigned order == (dist, idx) lexicographic.
//
// Prologue fused: ONE build kernel (256 blocks x 256 thr) does histogram ->
// hierarchical scan -> scatter with 3 device-scope spin barriers. 256 blocks
// <= 256 CUs and it is the only kernel on the stream => all blocks resident
// by construction, spin barrier cannot deadlock; plain launch = capture-safe.
//
// BARRIER LESSONS:
//  r1: ACQUIRE polls emit buffer_inv (per-XCD L2 invalidate) PER POLL ->
//      ~15us/barrier of serialized cache maintenance.
//  r2: relaxed fetch_add(0) polls are RMWs -> serialized at the coherence
//      point; 256 pollers saturate it, arrivals queue behind polls ->
//      ~5-10us/barrier.
//  r3 (this): poll with relaxed atomic LOAD (global_load sc1): coherent at
//      the LLC, no cache maintenance, reads don't serialize. Arrival =
//      s_waitcnt vmcnt(0) + relaxed fetch_add. All cross-block data moves
//      via sc1 atomics, so no further fencing is needed.
//
// knn_search: 256 thr = 4 waves/block (occupancy: fewer, fatter blocks).
// wave = 8 queries x 8 slices. Main scan = quadrant-aligned 4x4x4 cell box,
// SHIFT-clamped to the grid (origin clamp [0,28]) so the box is always full
// 4x4x4. Guarantee: uncovered min-d2 >= 49. Each slice-lane owns 2 whole
// rows; the two candidate streams are 2x-unrolled so 4 loads stay in flight
// per lane (halves the latency-serialized iteration count). Per-lane sorted
// top-16 via med3 insert network (insert order is irrelevant: top-k set).
// Merge tree (masks 8,16,32); FINAL merge keeps only the min-half (bitonic,
// unsorted) since the gather is a set-sum -- redo bound via max-tree; cold
// redo path (P~1e-7/query) re-sorts first, then proceeds as before.
// Gather fused: lane = 4 channels x 16 lanes/query, 2 passes x 4 queries;
// float4 feature-row loads; output written directly.

typedef unsigned int uint;
typedef unsigned short ushort;
typedef short short2v __attribute__((ext_vector_type(2)));

#define NPTS   65536
#define NCELL  32768
#define BBLK   256
#define BTPB   256

static __device__ inline short2v u2s(uint v) { union { uint u; short2v s; } c; c.u = v; return c.s; }
static __device__ inline uint s2u(short2v v) { union { uint u; short2v s; } c; c.s = v; return c.u; }

static __device__ inline int dot2acc(short2v a, short2v b, int c) {
#if __has_builtin(__builtin_amdgcn_sdot2)
    return __builtin_amdgcn_sdot2(a, b, c, false);
#else
    return (int)a.x * (int)b.x + (int)a.y * (int)b.y + c;
#endif
}

// Arrive-and-spin grid barrier. Safe because all BBLK blocks are resident
// (BBLK <= #CUs, sole kernel). target = BBLK * phase.
static __device__ __forceinline__ void gridbar(uint* bar, uint target) {
    __syncthreads();
    if (threadIdx.x == 0) {
        // all prior sc1 data atomics complete before our arrival is visible
        asm volatile("s_waitcnt vmcnt(0)" ::: "memory");
        __hip_atomic_fetch_add(bar, 1u, __ATOMIC_RELAXED, __HIP_MEMORY_SCOPE_AGENT);
        // relaxed atomic LOAD poll: coherent (sc1), no cache ops, no RMW
        // serialization. ~100ns backoff.
        while (__hip_atomic_load(bar, __ATOMIC_RELAXED, __HIP_MEMORY_SCOPE_AGENT) < target)
            __builtin_amdgcn_s_sleep(4);
    }
    __syncthreads();
}

__global__ __launch_bounds__(BTPB) void build(const int* __restrict__ coords,
                                              uint* __restrict__ bar,
                                              uint* __restrict__ counts,
                                              uint* __restrict__ starts,
                                              uint* __restrict__ cursors,
                                              uint2* __restrict__ sorted) {
    __shared__ uint wsum[4];
    __shared__ uint rsum[4];
    int b = blockIdx.x, tid = threadIdx.x;
    int i = b * BTPB + tid;
    int lane = tid & 63, wv = tid >> 6;

    // ---- phase 1: histogram (counts zeroed by the preceding memset) ----
    int x = coords[3 * i + 0], y = coords[3 * i + 1], z = coords[3 * i + 2];
    int cell = (x >> 2) | ((y >> 2) << 5) | ((z >> 2) << 10);
    atomicAdd(&counts[cell], 1u);
    gridbar(bar, BBLK);

    // ---- phase 2a: block-local scan, 256 cells/block (blocks 0..127) ----
    uint* bsums = (uint*)sorted;   // 128 scratch uints; clobbered in phase 3
    uint c = 0, excl = 0;
    if (b < 128) {
        int t2 = b * 256 + tid;    // cell id
        c = __hip_atomic_load(&counts[t2], __ATOMIC_RELAXED, __HIP_MEMORY_SCOPE_AGENT);
        uint v = c;
#pragma unroll
        for (int off = 1; off < 64; off <<= 1) {
            uint u = __shfl_up(v, off, 64);
            if (lane >= off) v += u;
        }
        if (lane == 63) wsum[wv] = v;
        __syncthreads();
        uint woff = 0, btot = 0;
#pragma unroll
        for (int j = 0; j < 4; ++j) {
            uint w = wsum[j];
            woff += (j < wv) ? w : 0u;
            btot += w;
        }
        excl = woff + v - c;       // block-local exclusive prefix
        if (tid == 0)
            __hip_atomic_store(&bsums[b], btot, __ATOMIC_RELAXED, __HIP_MEMORY_SCOPE_AGENT);
    }
    gridbar(bar, 2 * BBLK);

    // ---- phase 2b: cross-block offset, write starts/cursors ----
    if (b < 128) {
        uint s = 0;
        if (tid < 128 && tid < b)
            s = __hip_atomic_load(&bsums[tid], __ATOMIC_RELAXED, __HIP_MEMORY_SCOPE_AGENT);
#pragma unroll
        for (int off = 32; off; off >>= 1) s += __shfl_xor(s, off, 64);
        if (lane == 0) rsum[wv] = s;
        __syncthreads();
        uint blockoff = rsum[0] + rsum[1] + rsum[2] + rsum[3];
        int t2 = b * 256 + tid;
        uint st = blockoff + excl;
        starts[t2] = st;
        __hip_atomic_store(&cursors[t2], st, __ATOMIC_RELAXED, __HIP_MEMORY_SCOPE_AGENT);
        if (t2 == NCELL - 1) starts[NCELL] = st + c;   // = 65536
    }
    gridbar(bar, 3 * BBLK);

    // ---- phase 3: scatter (x,y,z,cell kept in registers from phase 1) ----
    uint pos = atomicAdd(&cursors[cell], 1u);
    sorted[pos] = make_uint2((uint)(x | (y << 16)), (uint)(i | (z << 16)));
}

__global__ __launch_bounds__(256, 8) void knn_search(const uint* __restrict__ starts,
                                                     const uint2* __restrict__ sorted,
                                                     const float* __restrict__ feat,
                                                     float* __restrict__ out) {
    // XCD-chunked swizzle: consecutive logical blocks -> same XCD L2.
    int blk  = (blockIdx.x & 7) * 256 + (blockIdx.x >> 3);   // 2048 blocks
    int wave = threadIdx.x >> 6;                             // 4 waves/block
    int lane = threadIdx.x & 63;
    int qslot = lane & 7;
    int slice = lane >> 3;
    int qpos = blk * 32 + wave * 8 + qslot;

    uint2 me = sorted[qpos];
    uint qxy = me.x;                       // qx | qy<<16
    uint qzp = me.y & 0xFFFF0000u;         // qz<<16
    uint qidx = me.y & 0xFFFFu;            // original index
    int qx = (int)(me.x & 0xFFFFu);
    int qy = (int)(me.x >> 16);
    int qz = (int)(me.y >> 16);
    int cx = qx >> 2, cy = qy >> 2, cz = qz >> 2;

    uint k[16];
#pragma unroll
    for (int j = 0; j < 16; ++j) k[j] = 0xFFFFFFFFu;

    auto insert1 = [&](uint2 pt) {
        short2v A = u2s(pt.x) - u2s(qxy);          // (dx, dy)
        short2v B = u2s(pt.y) - u2s(qzp);          // (idx, dz)
        uint Bu = s2u(B);
        short2v Bm = u2s(Bu & 0xFFFF0000u);        // (0, dz)
        int d2 = dot2acc(A, A, dot2acc(Bm, Bm, 0));
        uint key = ((uint)d2 << 16) + (Bu & 0xFFFFu);
        // in-place descending med3 chain: 15 independent ops (reads old j-1)
#pragma unroll
        for (int j = 15; j >= 1; --j)
            asm("v_med3_u32 %0, %1, %2, %3"
                : "=v"(k[j]) : "v"(k[j - 1]), "v"(k[j]), "v"(key));
        k[0] = min(k[0], key);
    };

    // sliced scan (stride 8 across slices) -- used only by the cold redo path
    auto scan8 = [&](uint p0, uint p1) {
        for (uint p = p0 + (uint)slice; p < p1; p += 8u) insert1(sorted[p]);
    };

    // bitonic min-half with partner lane (lane ^ mask): k becomes a bitonic
    // sequence holding the exact top-16 SET of the pair
    auto merge_min = [&](int mask) {
        uint b[16];
#pragma unroll
        for (int j = 0; j < 16; ++j) b[j] = __shfl_xor(k[j], mask, 64);
#pragma unroll
        for (int j = 0; j < 16; ++j) k[j] = min(k[j], b[15 - j]);
    };
    // bitonic cleanup: sorts the bitonic sequence ascending
    auto clean = [&]() {
#pragma unroll
        for (int d = 8; d >= 1; d >>= 1) {
#pragma unroll
            for (int i = 0; i < 16; ++i) {
                if ((i & d) == 0) {
                    uint lo = min(k[i], k[i + d]);
                    uint hi = max(k[i], k[i + d]);
                    k[i] = lo;
                    k[i + d] = hi;
                }
            }
        }
    };
    auto merge = [&](int mask) { merge_min(mask); clean(); };
    auto merge_all = [&]() { merge(8); merge(16); merge(32); };

    // ---- quadrant-aligned 4x4x4 box, SHIFT-clamped (always full size) ----
    int xa = min(max(cx - ((qx & 3) < 2 ? 2 : 1), 0), 28);
    int ya = min(max(cy - ((qy & 3) < 2 ? 2 : 1), 0), 28);
    int za = min(max(cz - ((qz & 3) < 2 ? 2 : 1), 0), 28);

    // lane owns rows rid = slice and slice+8;  rid -> (y = ya+(rid&3), z = za+(rid>>2))
    // 2x-unrolled: 4 predicated loads in flight per iteration.
    {
        int rbA = ((ya + (slice & 3)) << 5) | ((za + (slice >> 2)) << 10);
        int rbB = ((ya + (slice & 3)) << 5) | ((za + 2 + (slice >> 2)) << 10);
        uint pA = starts[rbA + xa], eA = starts[rbA + xa + 4];
        uint pB = starts[rbB + xa], eB = starts[rbB + xa + 4];
        while (__any((pA < eA) || (pB < eB))) {
            bool a0 = pA < eA, a1 = pA + 1 < eA;
            bool b0 = pB < eB, b1 = pB + 1 < eB;
            uint2 A0, A1, B0, B1;
            if (a0) A0 = sorted[pA];
            if (a1) A1 = sorted[pA + 1];
            if (b0) B0 = sorted[pB];
            if (b1) B1 = sorted[pB + 1];
            pA += (a0 ? 1u : 0u) + (a1 ? 1u : 0u);
            pB += (b0 ? 1u : 0u) + (b1 ? 1u : 0u);
            if (a0) insert1(A0);
            if (b0) insert1(B0);
            if (a1) insert1(A1);
            if (b1) insert1(B1);
        }
    }
    // exact top-16 SET over the box (final merge leaves k bitonic-unsorted;
    // the gather is a set-sum so order is irrelevant on the hot path)
    merge(8); merge(16); merge_min(32);
    uint mx = k[0];
#pragma unroll
    for (int j = 1; j < 16; ++j) mx = max(mx, k[j]);

    // ---- cold redo: uncovered space has min-d2 >= 49 (P ~ 1e-7/query) ----
    bool redo = (mx >> 16) >= 49u;
    if (__any(redo)) {
        clean();   // restore sorted order: merge machinery needs sorted inputs
        // triggered queries: discard everything, rescan from scratch (sliced).
        // others: keep slice 0 only (slices!=0 must reset before re-merge).
        if (redo || slice != 0) {
#pragma unroll
            for (int j = 0; j < 16; ++j) k[j] = 0xFFFFFFFFu;
        }
        if (redo) {
            int xl = max(cx - 2, 0), xh = min(cx + 2, 31);
            int yl = max(cy - 2, 0), yh = min(cy + 2, 31);
            int zl = max(cz - 2, 0), zh = min(cz + 2, 31);
            for (int z = zl; z <= zh; ++z)
                for (int y = yl; y <= yh; ++y) {
                    int rb = (y << 5) | (z << 10);
                    scan8(starts[rb + xl], starts[rb + xh + 1]);
                }
        }
        merge_all();
        for (int r = 3; r < 32; ++r) {
            uint b = (uint)(4 * r - 3);
            bool active = (k[15] >> 16) >= b * b;
            if (!__any(active)) break;
            if (slice != 0) {
#pragma unroll
                for (int j = 0; j < 16; ++j) k[j] = 0xFFFFFFFFu;
            }
            if (active) {
                int z0 = cz - r < 0 ? 0 : cz - r;
                int z1 = cz + r > 31 ? 31 : cz + r;
                for (int z = z0; z <= z1; ++z) {
                    bool zface = (z == cz - r) || (z == cz + r);
                    int y0 = cy - r < 0 ? 0 : cy - r;
                    int y1 = cy + r > 31 ? 31 : cy + r;
                    for (int y = y0; y <= y1; ++y) {
                        bool face = zface || (y == cy - r) || (y == cy + r);
                        int rb = (y << 5) | (z << 10);
                        if (face) {
                            int x0 = cx - r < 0 ? 0 : cx - r;
                            int x1 = cx + r > 31 ? 31 : cx + r;
                            scan8(starts[rb + x0], starts[rb + x1 + 1]);
                        } else {
                            int xL = cx - r;
                            if (xL >= 0) scan8(starts[rb + xL], starts[rb + xL + 1]);
                            int xR = cx + r;
                            if (xR <= 31) scan8(starts[rb + xR], starts[rb + xR + 1]);
                        }
                    }
                }
            }
            merge_all();
        }
    }

    // ---- fused gather: float4 channels, 2 passes x 4 queries ----
    uint ki[16];
#pragma unroll
    for (int j = 0; j < 16; ++j) ki[j] = k[j] & 0xFFFFu;

    int ch = lane & 15;          // float4 channel group (4 channels)
    int qg = lane >> 4;          // query within pass
#pragma unroll
    for (int p = 0; p < 2; ++p) {
        int qs = p * 4 + qg;
        uint qorig = __shfl(qidx, qs, 64);
        float4 acc = make_float4(0.f, 0.f, 0.f, 0.f);
#pragma unroll
        for (int j = 0; j < 16; ++j) {
            uint nj = __shfl(ki[j], qs, 64);
            float4 v = reinterpret_cast<const float4*>(feat)[nj * 16u + (uint)ch];
            acc.x += v.x; acc.y += v.y; acc.z += v.z; acc.w += v.w;
        }
        reinterpret_cast<float4*>(out)[qorig * 16u + (uint)ch] = acc;
    }
}

extern "C" void kernel_launch(void* const* d_in, const int* in_sizes, int n_in,
                              void* d_out, int out_size, void* d_ws, size_t ws_size,
                              hipStream_t stream) {
    const int*   coords = (const int*)d_in[0];
    const float* feat   = (const float*)d_in[1];
    float*       out    = (float*)d_out;

    uint* W = (uint*)d_ws;
    uint*  bar     = W;                       // 8 uints (1 used), memset-zeroed
    uint*  counts  = W + 8;                   // 32768, memset-zeroed
    uint*  starts  = W + 32776;               // 32769
    uint*  cursors = W + 65548;               // 32768 (16B aligned)
    uint2* sorted  = (uint2*)(W + 98316);     // 65536 * 8 B (8B aligned)

    hipMemsetAsync(W, 0, (8 + NCELL) * sizeof(uint), stream);
    build<<<BBLK, BTPB, 0, stream>>>(coords, bar, counts, starts, cursors, sorted);
    knn_search<<<2048, 256, 0, stream>>>(starts, sorted, feat, out);
}

// Round 4
// 61.500 us; speedup vs baseline: 1.4198x; 1.2225x over previous
//
#include <hip/hip_runtime.h>

// Exact KNN (faiss-equivalent, (dist,idx)-lexicographic ties) + fused neighbor
// feature sum. N=65536 pts on 128^3 int grid, K=16, C=64.
//
// Cells = 4^3 coords -> 32^3 = 32768 cells, ~2 pts/cell. Key = (d2<<16)|idx
// (d2 <= 48387 < 2^16): unsigned order == (dist, idx) lexicographic.
//
// PROLOGUE (rounds 1-3 lesson): single-kernel grid barriers cost ~8us each
// on MI355X regardless of poll discipline (acquire-inv storm r1, RMW
// serialization r2, relaxed-load r3 still ~25us total). So: NO barriers.
// The global cell scan is replaced by CHUNK-LOCAL allocation: knn only needs
// contiguity of cells within a row (4 cells, fixed cy,cz), and any row lies
// inside one 256-cell chunk (full cx range x one cy-octet x one cz). Each
// scan block therefore: local scan of its 256 counts + ONE atomicAdd on a
// global cursor to reserve the chunk extent. Chunk bases are arrival-ordered
// (harmless permutation of 'sorted' at chunk granularity; keys embed the
// original idx so the top-k set is order-independent), cells are contiguous
// within each chunk. starts[cell+1] is no longer a valid row-end sentinel at
// chunk edges -> explicit ends[] = starts+count, used for all range ends.
// 5 cheap dispatches; dispatch boundaries are the (free, driver) barriers.
//
// knn_search: 256 thr = 4 waves/block. wave = 8 queries x 8 slices. Main
// scan = quadrant-aligned 4x4x4 cell box, SHIFT-clamped to the grid (origin
// clamp [0,28]) so the box is always full 4x4x4. Guarantee: uncovered
// min-d2 >= 49. Each slice-lane owns 2 whole rows; the two candidate
// streams are 2x-unrolled so 4 loads stay in flight per lane. Per-lane
// sorted top-16 via med3 insert network (insert order irrelevant: top-k
// set). Merge tree (masks 8,16,32); FINAL merge keeps only the min-half
// (bitonic, unsorted) since the gather is a set-sum -- redo bound via
// max-tree; cold redo path (P~1e-7/query) re-sorts first, then proceeds.
// Gather fused: lane = 4 channels x 16 lanes/query, 2 passes x 4 queries;
// float4 feature-row loads; output written directly.

typedef unsigned int uint;
typedef unsigned short ushort;
typedef short short2v __attribute__((ext_vector_type(2)));

#define NPTS   65536
#define NCELL  32768

static __device__ inline short2v u2s(uint v) { union { uint u; short2v s; } c; c.u = v; return c.s; }
static __device__ inline uint s2u(short2v v) { union { uint u; short2v s; } c; c.s = v; return c.u; }

static __device__ inline int dot2acc(short2v a, short2v b, int c) {
#if __has_builtin(__builtin_amdgcn_sdot2)
    return __builtin_amdgcn_sdot2(a, b, c, false);
#else
    return (int)a.x * (int)b.x + (int)a.y * (int)b.y + c;
#endif
}

__global__ __launch_bounds__(256) void cell_count(const int* __restrict__ coords,
                                                  uint* __restrict__ counts) {
    int i = blockIdx.x * 256 + threadIdx.x;
    int x = coords[3 * i + 0], y = coords[3 * i + 1], z = coords[3 * i + 2];
    int cell = (x >> 2) | ((y >> 2) << 5) | ((z >> 2) << 10);
    atomicAdd(&counts[cell], 1u);
}

// Chunk-local scan: block b owns cells [b*256, (b+1)*256) = full cx range x
// one cy-octet x one cz. One atomicAdd reserves the chunk's extent; cells
// are cell-id-ordered and contiguous WITHIN the chunk (all knn rows qualify).
__global__ __launch_bounds__(256) void scan_chunk(const uint* __restrict__ counts,
                                                  uint* __restrict__ gcur,
                                                  uint* __restrict__ starts,
                                                  uint* __restrict__ ends,
                                                  uint* __restrict__ cursors) {
    __shared__ uint wsum[4];
    __shared__ uint sbase;
    int tid = threadIdx.x;
    int lane = tid & 63, wv = tid >> 6;
    int cell = blockIdx.x * 256 + tid;
    uint c = counts[cell];
    uint v = c;
#pragma unroll
    for (int off = 1; off < 64; off <<= 1) {
        uint u = __shfl_up(v, off, 64);
        if (lane >= off) v += u;
    }
    if (lane == 63) wsum[wv] = v;
    __syncthreads();
    if (tid == 0)
        sbase = atomicAdd(gcur, wsum[0] + wsum[1] + wsum[2] + wsum[3]);
    __syncthreads();
    uint woff = 0;
#pragma unroll
    for (int j = 0; j < 4; ++j) woff += (j < wv) ? wsum[j] : 0u;
    uint st = sbase + woff + v - c;
    starts[cell]  = st;
    ends[cell]    = st + c;
    cursors[cell] = st;
}

__global__ __launch_bounds__(256) void cell_scatter(const int* __restrict__ coords,
                                                    uint* __restrict__ cursors,
                                                    uint2* __restrict__ sorted) {
    int i = blockIdx.x * 256 + threadIdx.x;
    int x = coords[3 * i + 0], y = coords[3 * i + 1], z = coords[3 * i + 2];
    int cell = (x >> 2) | ((y >> 2) << 5) | ((z >> 2) << 10);
    uint pos = atomicAdd(&cursors[cell], 1u);
    // packed for v_pk_sub_i16 / v_dot2: w0 = x | y<<16, w1 = idx | z<<16
    sorted[pos] = make_uint2((uint)(x | (y << 16)), (uint)(i | (z << 16)));
}

__global__ __launch_bounds__(256, 8) void knn_search(const uint* __restrict__ starts,
                                                     const uint* __restrict__ ends,
                                                     const uint2* __restrict__ sorted,
                                                     const float* __restrict__ feat,
                                                     float* __restrict__ out) {
    // XCD-chunked swizzle: consecutive logical blocks -> same XCD L2.
    int blk  = (blockIdx.x & 7) * 256 + (blockIdx.x >> 3);   // 2048 blocks
    int wave = threadIdx.x >> 6;                             // 4 waves/block
    int lane = threadIdx.x & 63;
    int qslot = lane & 7;
    int slice = lane >> 3;
    int qpos = blk * 32 + wave * 8 + qslot;

    uint2 me = sorted[qpos];
    uint qxy = me.x;                       // qx | qy<<16
    uint qzp = me.y & 0xFFFF0000u;         // qz<<16
    uint qidx = me.y & 0xFFFFu;            // original index
    int qx = (int)(me.x & 0xFFFFu);
    int qy = (int)(me.x >> 16);
    int qz = (int)(me.y >> 16);
    int cx = qx >> 2, cy = qy >> 2, cz = qz >> 2;

    uint k[16];
#pragma unroll
    for (int j = 0; j < 16; ++j) k[j] = 0xFFFFFFFFu;

    auto insert1 = [&](uint2 pt) {
        short2v A = u2s(pt.x) - u2s(qxy);          // (dx, dy)
        short2v B = u2s(pt.y) - u2s(qzp);          // (idx, dz)
        uint Bu = s2u(B);
        short2v Bm = u2s(Bu & 0xFFFF0000u);        // (0, dz)
        int d2 = dot2acc(A, A, dot2acc(Bm, Bm, 0));
        uint key = ((uint)d2 << 16) + (Bu & 0xFFFFu);
        // in-place descending med3 chain: 15 independent ops (reads old j-1)
#pragma unroll
        for (int j = 15; j >= 1; --j)
            asm("v_med3_u32 %0, %1, %2, %3"
                : "=v"(k[j]) : "v"(k[j - 1]), "v"(k[j]), "v"(key));
        k[0] = min(k[0], key);
    };

    // sliced scan (stride 8 across slices) -- used only by the cold redo path
    auto scan8 = [&](uint p0, uint p1) {
        for (uint p = p0 + (uint)slice; p < p1; p += 8u) insert1(sorted[p]);
    };

    // bitonic min-half with partner lane (lane ^ mask): k becomes a bitonic
    // sequence holding the exact top-16 SET of the pair
    auto merge_min = [&](int mask) {
        uint b[16];
#pragma unroll
        for (int j = 0; j < 16; ++j) b[j] = __shfl_xor(k[j], mask, 64);
#pragma unroll
        for (int j = 0; j < 16; ++j) k[j] = min(k[j], b[15 - j]);
    };
    // bitonic cleanup: sorts the bitonic sequence ascending
    auto clean = [&]() {
#pragma unroll
        for (int d = 8; d >= 1; d >>= 1) {
#pragma unroll
            for (int i = 0; i < 16; ++i) {
                if ((i & d) == 0) {
                    uint lo = min(k[i], k[i + d]);
                    uint hi = max(k[i], k[i + d]);
                    k[i] = lo;
                    k[i + d] = hi;
                }
            }
        }
    };
    auto merge = [&](int mask) { merge_min(mask); clean(); };
    auto merge_all = [&]() { merge(8); merge(16); merge(32); };

    // ---- quadrant-aligned 4x4x4 box, SHIFT-clamped (always full size) ----
    int xa = min(max(cx - ((qx & 3) < 2 ? 2 : 1), 0), 28);
    int ya = min(max(cy - ((qy & 3) < 2 ? 2 : 1), 0), 28);
    int za = min(max(cz - ((qz & 3) < 2 ? 2 : 1), 0), 28);

    // lane owns rows rid = slice and slice+8;  rid -> (y = ya+(rid&3), z = za+(rid>>2))
    // 2x-unrolled: 4 predicated loads in flight per iteration.
    // Row range = [starts[first cell], ends[last cell]] -- ends[] because
    // starts[c+1] is not a valid sentinel at chunk boundaries.
    {
        int rbA = ((ya + (slice & 3)) << 5) | ((za + (slice >> 2)) << 10);
        int rbB = ((ya + (slice & 3)) << 5) | ((za + 2 + (slice >> 2)) << 10);
        uint pA = starts[rbA + xa], eA = ends[rbA + xa + 3];
        uint pB = starts[rbB + xa], eB = ends[rbB + xa + 3];
        while (__any((pA < eA) || (pB < eB))) {
            bool a0 = pA < eA, a1 = pA + 1 < eA;
            bool b0 = pB < eB, b1 = pB + 1 < eB;
            uint2 A0, A1, B0, B1;
            if (a0) A0 = sorted[pA];
            if (a1) A1 = sorted[pA + 1];
            if (b0) B0 = sorted[pB];
            if (b1) B1 = sorted[pB + 1];
            pA += (a0 ? 1u : 0u) + (a1 ? 1u : 0u);
            pB += (b0 ? 1u : 0u) + (b1 ? 1u : 0u);
            if (a0) insert1(A0);
            if (b0) insert1(B0);
            if (a1) insert1(A1);
            if (b1) insert1(B1);
        }
    }
    // exact top-16 SET over the box (final merge leaves k bitonic-unsorted;
    // the gather is a set-sum so order is irrelevant on the hot path)
    merge(8); merge(16); merge_min(32);
    uint mx = k[0];
#pragma unroll
    for (int j = 1; j < 16; ++j) mx = max(mx, k[j]);

    // ---- cold redo: uncovered space has min-d2 >= 49 (P ~ 1e-7/query) ----
    bool redo = (mx >> 16) >= 49u;
    if (__any(redo)) {
        clean();   // restore sorted order: merge machinery needs sorted inputs
        // triggered queries: discard everything, rescan from scratch (sliced).
        // others: keep slice 0 only (slices!=0 must reset before re-merge).
        if (redo || slice != 0) {
#pragma unroll
            for (int j = 0; j < 16; ++j) k[j] = 0xFFFFFFFFu;
        }
        if (redo) {
            int xl = max(cx - 2, 0), xh = min(cx + 2, 31);
            int yl = max(cy - 2, 0), yh = min(cy + 2, 31);
            int zl = max(cz - 2, 0), zh = min(cz + 2, 31);
            for (int z = zl; z <= zh; ++z)
                for (int y = yl; y <= yh; ++y) {
                    int rb = (y << 5) | (z << 10);
                    scan8(starts[rb + xl], ends[rb + xh]);
                }
        }
        merge_all();
        for (int r = 3; r < 32; ++r) {
            uint b = (uint)(4 * r - 3);
            bool active = (k[15] >> 16) >= b * b;
            if (!__any(active)) break;
            if (slice != 0) {
#pragma unroll
                for (int j = 0; j < 16; ++j) k[j] = 0xFFFFFFFFu;
            }
            if (active) {
                int z0 = cz - r < 0 ? 0 : cz - r;
                int z1 = cz + r > 31 ? 31 : cz + r;
                for (int z = z0; z <= z1; ++z) {
                    bool zface = (z == cz - r) || (z == cz + r);
                    int y0 = cy - r < 0 ? 0 : cy - r;
                    int y1 = cy + r > 31 ? 31 : cy + r;
                    for (int y = y0; y <= y1; ++y) {
                        bool face = zface || (y == cy - r) || (y == cy + r);
                        int rb = (y << 5) | (z << 10);
                        if (face) {
                            int x0 = cx - r < 0 ? 0 : cx - r;
                            int x1 = cx + r > 31 ? 31 : cx + r;
                            scan8(starts[rb + x0], ends[rb + x1]);
                        } else {
                            int xL = cx - r;
                            if (xL >= 0) scan8(starts[rb + xL], ends[rb + xL]);
                            int xR = cx + r;
                            if (xR <= 31) scan8(starts[rb + xR], ends[rb + xR]);
                        }
                    }
                }
            }
            merge_all();
        }
    }

    // ---- fused gather: float4 channels, 2 passes x 4 queries ----
    uint ki[16];
#pragma unroll
    for (int j = 0; j < 16; ++j) ki[j] = k[j] & 0xFFFFu;

    int ch = lane & 15;          // float4 channel group (4 channels)
    int qg = lane >> 4;          // query within pass
#pragma unroll
    for (int p = 0; p < 2; ++p) {
        int qs = p * 4 + qg;
        uint qorig = __shfl(qidx, qs, 64);
        float4 acc = make_float4(0.f, 0.f, 0.f, 0.f);
#pragma unroll
        for (int j = 0; j < 16; ++j) {
            uint nj = __shfl(ki[j], qs, 64);
            float4 v = reinterpret_cast<const float4*>(feat)[nj * 16u + (uint)ch];
            acc.x += v.x; acc.y += v.y; acc.z += v.z; acc.w += v.w;
        }
        reinterpret_cast<float4*>(out)[qorig * 16u + (uint)ch] = acc;
    }
}

extern "C" void kernel_launch(void* const* d_in, const int* in_sizes, int n_in,
                              void* d_out, int out_size, void* d_ws, size_t ws_size,
                              hipStream_t stream) {
    const int*   coords = (const int*)d_in[0];
    const float* feat   = (const float*)d_in[1];
    float*       out    = (float*)d_out;

    uint* W = (uint*)d_ws;
    uint*  gcur    = W;                       // 8 uints (1 used), memset-zeroed
    uint*  counts  = W + 8;                   // 32768, memset-zeroed
    uint*  starts  = W + 32776;               // 32768
    uint*  ends    = W + 65544;               // 32768
    uint*  cursors = W + 98312;               // 32768
    uint2* sorted  = (uint2*)(W + 131080);    // 65536 * 8 B (8B aligned)

    hipMemsetAsync(W, 0, (8 + NCELL) * sizeof(uint), stream);
    cell_count<<<NPTS / 256, 256, 0, stream>>>(coords, counts);
    scan_chunk<<<NCELL / 256, 256, 0, stream>>>(counts, gcur, starts, ends, cursors);
    cell_scatter<<<NPTS / 256, 256, 0, stream>>>(coords, cursors, sorted);
    knn_search<<<2048, 256, 0, stream>>>(starts, ends, sorted, feat, out);
}